// Round 5
// baseline (338.962 us; speedup 1.0000x reference)
//
#include <hip/hip_runtime.h>
#include <hip/hip_cooperative_groups.h>

namespace cg = cooperative_groups;

// Problem constants
#define V_SZ 32000
#define E_SZ 128
#define H_SZ 32
#define L_SZ 64
#define B_SZ 32
#define M_TOT 2048   // L*B rows
#define K2 64        // 2H
#define NVT 125      // V/256 col-slices
#define NUNIT 500    // 125 col-slices x 4 row-groups (8 row-tiles each)
#define TPB 256

typedef __bf16 bf16x8 __attribute__((ext_vector_type(8)));
typedef float f32x4 __attribute__((ext_vector_type(4)));

__device__ __forceinline__ unsigned short f2bf(float f) {
    unsigned int u = __float_as_uint(f);
    u += 0x7FFFu + ((u >> 16) & 1u);   // round-to-nearest-even
    return (unsigned short)(u >> 16);
}

// ---------------------------------------------------------------------------
// Shared device phase functions (used by BOTH coop and split kernels)
// ---------------------------------------------------------------------------

// RNN for one wave w (0..31): 2 batch rows, h in regs, shfl recurrence.
__device__ __forceinline__ void rnn_wave(
    int w, int lane, const float* __restrict__ X,
    const float* __restrict__ i2h1, const float* __restrict__ i2h2,
    const float* __restrict__ hinit, unsigned short* __restrict__ hcat_u) {
    const int dir = w >> 4;
    const int b = (w & 15) * 2 + (lane >> 5);
    const int j = lane & 31;
    const int srcbase = lane & 32;
    const float* Wf = dir ? i2h2 : i2h1;
    float wh[H_SZ];
#pragma unroll
    for (int k = 0; k < H_SZ; ++k) wh[k] = Wf[(E_SZ + k) * H_SZ + j];
    float h = hinit[j];
    const float* Xd = X + dir * (L_SZ * B_SZ * H_SZ);
    int tt0 = dir ? (L_SZ - 1) : 0;
    float xcur = Xd[(tt0 * B_SZ + b) * H_SZ + j];
    for (int step = 0; step < L_SZ; ++step) {
        const int tt = dir ? (L_SZ - 1 - step) : step;
        int tn = dir ? (L_SZ - 2 - step) : (step + 1);
        tn = tn < 0 ? 0 : (tn > L_SZ - 1 ? L_SZ - 1 : tn);
        float xnext = Xd[(tn * B_SZ + b) * H_SZ + j];
        hcat_u[(tt * B_SZ + b) * K2 + dir * H_SZ + j] = f2bf(h);
        float a0 = xcur, a1 = 0.f, a2 = 0.f, a3 = 0.f;
#pragma unroll
        for (int k = 0; k < H_SZ; k += 4) {
            a0 += __shfl(h, srcbase | k, 64) * wh[k];
            a1 += __shfl(h, srcbase | (k + 1), 64) * wh[k + 1];
            a2 += __shfl(h, srcbase | (k + 2), 64) * wh[k + 2];
            a3 += __shfl(h, srcbase | (k + 3), 64) * wh[k + 3];
        }
        float x2 = (a0 + a1) + (a2 + a3);
        float e = __expf(2.f * x2);        // tanh = 1 - 2/(e^{2x}+1)
        h = 1.f - 2.f * __builtin_amdgcn_rcpf(e + 1.f);
        xcur = xnext;
    }
}

// Load this wave's resident B fragments for col-slice xcol (128 cols/wave).
__device__ __forceinline__ void load_bfrag(
    const __bf16* __restrict__ h2oT, int xcol, int wn, int lg, int lr,
    bf16x8 bfr[8][2]) {
    const int colbase = xcol * 256;
#pragma unroll
    for (int n = 0; n < 8; ++n) {
        int col = colbase + wn * 128 + n * 16 + lr;
        const __bf16* bp = h2oT + (size_t)col * K2 + lg * 8;
        bfr[n][0] = *(const bf16x8*)(bp);
        bfr[n][1] = *(const bf16x8*)(bp + 32);
    }
}

// One 64x256 tile-GEMM into acc (MFMA 16x16x32, B resident in bfr).
__device__ __forceinline__ void tile_gemm(
    const __bf16* __restrict__ hcat, int rowbase, int wm, int lg, int lr,
    const bf16x8 bfr[8][2], f32x4 acc[2][8]) {
    bf16x8 af[2][2];
#pragma unroll
    for (int m = 0; m < 2; ++m) {
        int row = rowbase + wm * 32 + m * 16 + lr;
#pragma unroll
        for (int kh = 0; kh < 2; ++kh)
            af[m][kh] = *(const bf16x8*)(hcat + row * K2 + kh * 32 + lg * 8);
    }
#pragma unroll
    for (int m = 0; m < 2; ++m)
#pragma unroll
        for (int n = 0; n < 8; ++n) acc[m][n] = (f32x4){0.f, 0.f, 0.f, 0.f};
#pragma unroll
    for (int n = 0; n < 8; ++n)
#pragma unroll
        for (int m = 0; m < 2; ++m) {
            acc[m][n] = __builtin_amdgcn_mfma_f32_16x16x32_bf16(af[m][0], bfr[n][0], acc[m][n], 0, 0, 0);
            acc[m][n] = __builtin_amdgcn_mfma_f32_16x16x32_bf16(af[m][1], bfr[n][1], acc[m][n], 0, 0, 0);
        }
}

// Phase-1 body for one unit u: 8 row-tiles of sum-exp partials.
// tsum: 2x64 floats of LDS.
__device__ __forceinline__ void sumexp_unit(
    const __bf16* __restrict__ hcat, const bf16x8 bfr[8][2], int u,
    int tid, int wm, int wn, int lg, int lr, float (*tsum)[64],
    float* __restrict__ Asum) {
    const int xcol = u >> 2, y0 = (u & 3) * 8;
    for (int jt = 0; jt < 8; ++jt) {
        const int rowbase = (y0 + jt) * 64;
        f32x4 acc[2][8];
        tile_gemm(hcat, rowbase, wm, lg, lr, bfr, acc);
        float rs[2][4];
#pragma unroll
        for (int m = 0; m < 2; ++m)
#pragma unroll
            for (int r = 0; r < 4; ++r) {
                float s = 0.f;
#pragma unroll
                for (int n = 0; n < 8; ++n) s += __expf(acc[m][n][r]);
                rs[m][r] = s;
            }
#pragma unroll
        for (int mask = 1; mask < 16; mask <<= 1)
#pragma unroll
            for (int m = 0; m < 2; ++m)
#pragma unroll
                for (int r = 0; r < 4; ++r)
                    rs[m][r] += __shfl_xor(rs[m][r], mask, 64);
        if (lr == 0) {
#pragma unroll
            for (int m = 0; m < 2; ++m)
#pragma unroll
                for (int r = 0; r < 4; ++r)
                    tsum[wn][wm * 32 + m * 16 + lg * 4 + r] = rs[m][r];
        }
        __syncthreads();
        if (tid < 64)
            Asum[xcol * M_TOT + rowbase + tid] = tsum[0][tid] + tsum[1][tid];
        __syncthreads();
    }
}

// Phase-3 body for one unit u: 8 row-tiles recompute + coalesced write.
// cbuf: 32x260 floats of LDS.
__device__ __forceinline__ void write_unit(
    const __bf16* __restrict__ hcat, const bf16x8 bfr[8][2], int u,
    int tid, int wm, int wn, int lg, int lr, float* cbuf,
    const float* __restrict__ lse, float* __restrict__ out) {
    const int xcol = u >> 2, y0 = (u & 3) * 8;
    const int colbase = xcol * 256;
    for (int jt = 0; jt < 8; ++jt) {
        const int rowbase = (y0 + jt) * 64;
        f32x4 acc[2][8];
        tile_gemm(hcat, rowbase, wm, lg, lr, bfr, acc);
        float lsev[2][4];
#pragma unroll
        for (int m = 0; m < 2; ++m)
#pragma unroll
            for (int r = 0; r < 4; ++r)
                lsev[m][r] = lse[rowbase + wm * 32 + m * 16 + lg * 4 + r];
#pragma unroll
        for (int c = 0; c < 2; ++c) {
            __syncthreads();                  // WAR guard (chunk & tile reuse)
#pragma unroll
            for (int n = 0; n < 8; ++n)
#pragma unroll
                for (int r = 0; r < 4; ++r)
                    cbuf[(wm * 16 + lg * 4 + r) * 260 + wn * 128 + n * 16 + lr] =
                        acc[c][n][r] - lsev[c][r];
            __syncthreads();
#pragma unroll
            for (int it = 0; it < 8; ++it) {
                int idx4 = it * 256 + tid;
                int lrow = idx4 >> 6;
                int col = (idx4 & 63) << 2;
                int grow = rowbase + (lrow >> 4) * 32 + c * 16 + (lrow & 15);
                f32x4 v = *(const f32x4*)&cbuf[lrow * 260 + col];
                *(f32x4*)(out + (size_t)grow * V_SZ + colbase + col) = v;
            }
        }
    }
}

// ---------------------------------------------------------------------------
// Fused cooperative kernel (grid-stride; works for any grid >= 16)
// ---------------------------------------------------------------------------
__global__ __launch_bounds__(TPB, 2) void k_fused(
    const int* __restrict__ inp, const float* __restrict__ we,
    const float* __restrict__ i2h1, const float* __restrict__ i2h2,
    const float* __restrict__ h2o, const float* __restrict__ bias,
    const float* __restrict__ hinit,
    float* __restrict__ X, unsigned short* __restrict__ hcat_u,
    unsigned short* __restrict__ h2oT_u, float* __restrict__ Asum,
    float* __restrict__ lse, float* __restrict__ out)
{
    cg::grid_group gg = cg::this_grid();
    __shared__ float smem[8320];               // 33,280 B, phase-overlaid
    const int tid = threadIdx.x;
    const int p = blockIdx.x, g = gridDim.x;
    const int wave = tid >> 6, lane = tid & 63;
    const int wm = wave >> 1, wn = wave & 1;
    const int lg = lane >> 4, lr = lane & 15;
    const __bf16* hcat = (const __bf16*)hcat_u;
    const __bf16* h2oT = (const __bf16*)h2oT_u;

    // ---- phase 0a: emb-GEMM (units 0..127) + h2o transpose (128..252) ----
    for (int q = p; q < 253; q += g) {
        if (q < 128) {
            const int d = q >> 6, t = q & 63;
            const float* W = d ? i2h2 : i2h1;
            float* Wl = smem;                  // 16 KB
            __syncthreads();
            for (int i = tid; i < E_SZ * H_SZ; i += TPB) Wl[i] = W[i];
            __syncthreads();
            const int j = tid & 31, b0r = tid >> 5;
            const float bj = bias[j];
            for (int bb = b0r; bb < B_SZ; bb += 8) {
                const int idx = inp[t * B_SZ + bb];
                const float* er = we + (size_t)idx * E_SZ;
                float acc = bj;
#pragma unroll
                for (int k0 = 0; k0 < E_SZ; k0 += 4) {
                    f32x4 e4 = *(const f32x4*)(er + k0);
                    acc += e4.x * Wl[(k0 + 0) * H_SZ + j];
                    acc += e4.y * Wl[(k0 + 1) * H_SZ + j];
                    acc += e4.z * Wl[(k0 + 2) * H_SZ + j];
                    acc += e4.w * Wl[(k0 + 3) * H_SZ + j];
                }
                X[((d * L_SZ + t) * B_SZ + bb) * H_SZ + j] = acc;
            }
        } else {
            const int v = (q - 128) * 256 + tid;   // [0,32000) exact
            unsigned int* dst = (unsigned int*)(h2oT_u + (size_t)v * K2);
#pragma unroll
            for (int k = 0; k < K2; k += 2) {
                float a = h2o[(size_t)k * V_SZ + v];
                float b = h2o[(size_t)(k + 1) * V_SZ + v];
                dst[k >> 1] = (unsigned int)f2bf(a) | ((unsigned int)f2bf(b) << 16);
            }
        }
    }
    __threadfence();
    gg.sync();

    // ---- phase 0b: RNN (32 waves on blocks p<8) ----
    if (p < 8) rnn_wave(p * 4 + wave, lane, X, i2h1, i2h2, hinit, hcat_u);
    __threadfence();
    gg.sync();

    // ---- phase 1: sum-exp partials ----
    {
        float (*tsum)[64] = (float(*)[64])(smem + 8192);
        for (int u = p; u < NUNIT; u += g) {
            bf16x8 bfr[8][2];
            load_bfrag(h2oT, u >> 2, wn, lg, lr, bfr);
            sumexp_unit(hcat, bfr, u, tid, wm, wn, lg, lr, tsum, Asum);
        }
    }
    __threadfence();
    gg.sync();

    // ---- phase 2: lse ----
    if (p < 8) {
        const int row = p * 256 + tid;
        float s = 0.f;
        for (int i = 0; i < NVT; ++i) s += Asum[i * M_TOT + row];
        lse[row] = logf(s);
    }
    __threadfence();
    gg.sync();

    // ---- phase 3: recompute + write ----
    for (int u = p; u < NUNIT; u += g) {
        bf16x8 bfr[8][2];
        load_bfrag(h2oT, u >> 2, wn, lg, lr, bfr);
        write_unit(hcat, bfr, u, tid, wm, wn, lg, lr, smem, lse, out);
    }
}

// ---------------------------------------------------------------------------
// Fallback split kernels (regular launches)
// ---------------------------------------------------------------------------
__global__ __launch_bounds__(1024) void k_prep(
    const int* __restrict__ inp, const float* __restrict__ we,
    const float* __restrict__ i2h1, const float* __restrict__ i2h2,
    const float* __restrict__ bias, const float* __restrict__ h2o,
    float* __restrict__ X, unsigned short* __restrict__ h2oT) {
    const int tid = threadIdx.x;
    if (blockIdx.x < 128) {
        const int d = blockIdx.x >> 6;
        const int t = blockIdx.x & 63;
        const int b = tid >> 5, j = tid & 31;
        const float* W = d ? i2h2 : i2h1;
        __shared__ float Wl[E_SZ * H_SZ];
        for (int i = tid; i < E_SZ * H_SZ; i += 1024) Wl[i] = W[i];
        __syncthreads();
        const int idx = inp[t * B_SZ + b];
        const float* er = we + (size_t)idx * E_SZ;
        float acc = bias[j];
#pragma unroll
        for (int k0 = 0; k0 < E_SZ; k0 += 4) {
            f32x4 e4 = *(const f32x4*)(er + k0);
            acc += e4.x * Wl[(k0 + 0) * H_SZ + j];
            acc += e4.y * Wl[(k0 + 1) * H_SZ + j];
            acc += e4.z * Wl[(k0 + 2) * H_SZ + j];
            acc += e4.w * Wl[(k0 + 3) * H_SZ + j];
        }
        X[((d * L_SZ + t) * B_SZ + b) * H_SZ + j] = acc;
    } else {
        const int v = (blockIdx.x - 128) * 1024 + tid;
        if (v < V_SZ) {
            unsigned int* dst = (unsigned int*)(h2oT + (size_t)v * K2);
#pragma unroll
            for (int k = 0; k < K2; k += 2) {
                float a = h2o[(size_t)k * V_SZ + v];
                float b = h2o[(size_t)(k + 1) * V_SZ + v];
                dst[k >> 1] = (unsigned int)f2bf(a) | ((unsigned int)f2bf(b) << 16);
            }
        }
    }
}

__global__ __launch_bounds__(64) void k_rnn(
    const float* __restrict__ X, const float* __restrict__ i2h1,
    const float* __restrict__ i2h2, const float* __restrict__ hinit,
    unsigned short* __restrict__ hcat) {
    rnn_wave(blockIdx.x, threadIdx.x, X, i2h1, i2h2, hinit, hcat);
}

__global__ __launch_bounds__(256, 2) void k_pass_a2(
    const __bf16* __restrict__ hcat, const __bf16* __restrict__ h2oT,
    float* __restrict__ Asum) {
    const int tid = threadIdx.x;
    const int wave = tid >> 6, lane = tid & 63;
    const int wm = wave >> 1, wn = wave & 1;
    const int lg = lane >> 4, lr = lane & 15;
    const int u = blockIdx.x * 4 + blockIdx.y;   // xcol = u>>2, y0 = (u&3)*8
    __shared__ float tsum[2][64];
    bf16x8 bfr[8][2];
    load_bfrag(h2oT, u >> 2, wn, lg, lr, bfr);
    sumexp_unit(hcat, bfr, u, tid, wm, wn, lg, lr, tsum, Asum);
}

__global__ __launch_bounds__(256) void k_lse(
    const float* __restrict__ Asum, float* __restrict__ lse) {
    const int row = blockIdx.x * 256 + threadIdx.x;
    float s = 0.f;
    for (int i = 0; i < NVT; ++i) s += Asum[i * M_TOT + row];
    lse[row] = logf(s);
}

__global__ __launch_bounds__(256, 2) void k_pass_b2(
    const __bf16* __restrict__ hcat, const __bf16* __restrict__ h2oT,
    const float* __restrict__ lse, float* __restrict__ out) {
    const int tid = threadIdx.x;
    const int wave = tid >> 6, lane = tid & 63;
    const int wm = wave >> 1, wn = wave & 1;
    const int lg = lane >> 4, lr = lane & 15;
    const int u = blockIdx.x * 4 + blockIdx.y;
    __shared__ float cbuf[32 * 260];
    bf16x8 bfr[8][2];
    load_bfrag(h2oT, u >> 2, wn, lg, lr, bfr);
    write_unit(hcat, bfr, u, tid, wm, wn, lg, lr, cbuf, lse, out);
}

// ---------------------------------------------------------------------------
extern "C" void kernel_launch(void* const* d_in, const int* in_sizes, int n_in,
                              void* d_out, int out_size, void* d_ws, size_t ws_size,
                              hipStream_t stream) {
    (void)in_sizes; (void)n_in; (void)out_size; (void)ws_size;
    const int*   inp   = (const int*)d_in[0];
    const float* we    = (const float*)d_in[1];
    const float* i2h1  = (const float*)d_in[2];
    const float* i2h2  = (const float*)d_in[3];
    const float* h2o   = (const float*)d_in[4];
    const float* bias  = (const float*)d_in[5];
    const float* hinit = (const float*)d_in[6];
    float* out = (float*)d_out;
    char* ws = (char*)d_ws;
    float*          X      = (float*)(ws);                    // 524288 B
    unsigned short* hcat_u = (unsigned short*)(ws + 524288);  // 262144 B
    unsigned short* h2oT_u = (unsigned short*)(ws + 786432);  // 4096000 B
    float*          Asum   = (float*)(ws + 4882432);          // 1024000 B
    float*          lse    = (float*)(ws + 5906432);          // 8192 B

    // Try the fused cooperative kernel with a runtime-validated grid.
    hipError_t e = hipErrorUnknown;
    int occ = 0;
    if (hipOccupancyMaxActiveBlocksPerMultiprocessor(&occ, k_fused, TPB, 0)
            == hipSuccess && occ > 0) {
        int grid = occ * 256;                 // 256 CUs on MI355X
        if (grid > NUNIT) grid = NUNIT;
        if (grid >= 16) {
            void* args[] = {
                (void*)&inp, (void*)&we, (void*)&i2h1, (void*)&i2h2,
                (void*)&h2o, (void*)&bias, (void*)&hinit, (void*)&X,
                (void*)&hcat_u, (void*)&h2oT_u, (void*)&Asum, (void*)&lse,
                (void*)&out};
            e = hipLaunchCooperativeKernel((void*)k_fused, dim3(grid),
                                           dim3(TPB), args, 0, stream);
        }
    }
    if (e != hipSuccess) {
        // Fallback: split pipeline (same device math).
        k_prep<<<160, 1024, 0, stream>>>(inp, we, i2h1, i2h2, bias, h2o, X, h2oT_u);
        k_rnn<<<32, 64, 0, stream>>>(X, i2h1, i2h2, hinit, hcat_u);
        k_pass_a2<<<dim3(NVT, 4), 256, 0, stream>>>(
            (const __bf16*)hcat_u, (const __bf16*)h2oT_u, Asum);
        k_lse<<<8, 256, 0, stream>>>(Asum, lse);
        k_pass_b2<<<dim3(NVT, 4), 256, 0, stream>>>(
            (const __bf16*)hcat_u, (const __bf16*)h2oT_u, lse, out);
    }
}

// Round 6
// 186.896 us; speedup vs baseline: 1.8136x; 1.8136x over previous
//
#include <hip/hip_runtime.h>

// Problem constants
#define V_SZ 32000
#define E_SZ 128
#define H_SZ 32
#define L_SZ 64
#define B_SZ 32
#define M_TOT 2048   // L*B rows
#define K2 64        // 2H
#define NVT 125      // V/256 col-slices
#define NMT 32       // M_TOT/64 row-tiles

typedef __bf16 bf16x8 __attribute__((ext_vector_type(8)));
typedef float f32x4 __attribute__((ext_vector_type(4)));

__device__ __forceinline__ unsigned short f2bf(float f) {
    unsigned int u = __float_as_uint(f);
    u += 0x7FFFu + ((u >> 16) & 1u);   // round-to-nearest-even
    return (unsigned short)(u >> 16);
}

// ---------------------------------------------------------------------------
// Proven device helpers (R5): resident B fragments + one 64x256 tile GEMM.
// C layout: row = wm*32 + m*16 + lg*4 + r, col = wn*128 + n*16 + lr.
// ---------------------------------------------------------------------------
__device__ __forceinline__ void load_bfrag(
    const __bf16* __restrict__ h2oT, int xcol, int wn, int lg, int lr,
    bf16x8 bfr[8][2]) {
    const int colbase = xcol * 256;
#pragma unroll
    for (int n = 0; n < 8; ++n) {
        int col = colbase + wn * 128 + n * 16 + lr;
        const __bf16* bp = h2oT + (size_t)col * K2 + lg * 8;
        bfr[n][0] = *(const bf16x8*)(bp);
        bfr[n][1] = *(const bf16x8*)(bp + 32);
    }
}

__device__ __forceinline__ void tile_gemm(
    const __bf16* __restrict__ hcat, int rowbase, int wm, int lg, int lr,
    const bf16x8 bfr[8][2], f32x4 acc[2][8]) {
    bf16x8 af[2][2];
#pragma unroll
    for (int m = 0; m < 2; ++m) {
        int row = rowbase + wm * 32 + m * 16 + lr;
#pragma unroll
        for (int kh = 0; kh < 2; ++kh)
            af[m][kh] = *(const bf16x8*)(hcat + row * K2 + kh * 32 + lg * 8);
    }
#pragma unroll
    for (int m = 0; m < 2; ++m)
#pragma unroll
        for (int n = 0; n < 8; ++n) acc[m][n] = (f32x4){0.f, 0.f, 0.f, 0.f};
#pragma unroll
    for (int n = 0; n < 8; ++n)
#pragma unroll
        for (int m = 0; m < 2; ++m) {
            acc[m][n] = __builtin_amdgcn_mfma_f32_16x16x32_bf16(af[m][0], bfr[n][0], acc[m][n], 0, 0, 0);
            acc[m][n] = __builtin_amdgcn_mfma_f32_16x16x32_bf16(af[m][1], bfr[n][1], acc[m][n], 0, 0, 0);
        }
}

// ---------------------------------------------------------------------------
// Kernel 1: blocks 0..124  -> transpose+convert h2o -> h2oT (256 rows each)
//           blocks 125..156 -> emb-GEMM into LDS + RNN recurrence (1 dir,
//           2 batch rows per block; wave 0 runs the recurrence).
// ---------------------------------------------------------------------------
__global__ __launch_bounds__(256) void k_prep_rnn(
    const int* __restrict__ inp, const float* __restrict__ we,
    const float* __restrict__ i2h1, const float* __restrict__ i2h2,
    const float* __restrict__ h2o, const float* __restrict__ bias,
    const float* __restrict__ hinit,
    unsigned short* __restrict__ hcat_u, unsigned short* __restrict__ h2oT_u) {
    const int tid = threadIdx.x;
    const int p = blockIdx.x;
    if (p < 125) {
        // ---- h2o transpose (proven body) ----
        const int v = p * 256 + tid;               // [0,32000) exact
        unsigned int* dst = (unsigned int*)(h2oT_u + (size_t)v * K2);
#pragma unroll
        for (int k = 0; k < K2; k += 2) {
            float a = h2o[(size_t)k * V_SZ + v];
            float b = h2o[(size_t)(k + 1) * V_SZ + v];
            dst[k >> 1] = (unsigned int)f2bf(a) | ((unsigned int)f2bf(b) << 16);
        }
        return;
    }
    // ---- emb + RNN block ----
    const int w2 = p - 125;                        // 0..31
    const int dir = w2 >> 4;
    const int bpair = w2 & 15;
    const float* W = dir ? i2h2 : i2h1;
    __shared__ float Xl[L_SZ * 2 * H_SZ];          // 16 KB: X[t][bb][j]
    {
        const int j = tid & 31, bb = (tid >> 5) & 1, to = tid >> 6;
        const int b = bpair * 2 + bb;
        const float bj = bias[j];
        for (int tt = 0; tt < 16; ++tt) {
            const int t = to * 16 + tt;
            const int idx = inp[t * B_SZ + b];
            const float* er = we + (size_t)idx * E_SZ;
            float acc = bj;
#pragma unroll
            for (int k0 = 0; k0 < E_SZ; k0 += 4) {
                f32x4 e4 = *(const f32x4*)(er + k0);
                acc += e4.x * W[(k0 + 0) * H_SZ + j];
                acc += e4.y * W[(k0 + 1) * H_SZ + j];
                acc += e4.z * W[(k0 + 2) * H_SZ + j];
                acc += e4.w * W[(k0 + 3) * H_SZ + j];
            }
            Xl[(t * 2 + bb) * H_SZ + j] = acc;
        }
    }
    __syncthreads();
    if (tid < 64) {
        // recurrence: lanes 0-31 = row bpair*2, lanes 32-63 = row bpair*2+1
        const int lane = tid;
        const int bb = lane >> 5;
        const int b = bpair * 2 + bb;
        const int j = lane & 31;
        const int srcbase = lane & 32;
        float wh[H_SZ];
#pragma unroll
        for (int k = 0; k < H_SZ; ++k) wh[k] = W[(E_SZ + k) * H_SZ + j];
        float h = hinit[j];
        for (int step = 0; step < L_SZ; ++step) {
            const int tt = dir ? (L_SZ - 1 - step) : step;
            hcat_u[(tt * B_SZ + b) * K2 + dir * H_SZ + j] = f2bf(h);
            float a0 = Xl[(tt * 2 + bb) * H_SZ + j];
            float a1 = 0.f, a2 = 0.f, a3 = 0.f;
#pragma unroll
            for (int k = 0; k < H_SZ; k += 4) {
                a0 += __shfl(h, srcbase | k, 64) * wh[k];
                a1 += __shfl(h, srcbase | (k + 1), 64) * wh[k + 1];
                a2 += __shfl(h, srcbase | (k + 2), 64) * wh[k + 2];
                a3 += __shfl(h, srcbase | (k + 3), 64) * wh[k + 3];
            }
            float x2 = (a0 + a1) + (a2 + a3);
            float e = __expf(2.f * x2);            // tanh = 1 - 2/(e^{2x}+1)
            h = 1.f - 2.f * __builtin_amdgcn_rcpf(e + 1.f);
        }
    }
}

// ---------------------------------------------------------------------------
// Kernel 2 (pass A, max-free): one 64x256 tile per block, grid (125, 32).
// ---------------------------------------------------------------------------
__global__ __launch_bounds__(256) void k_pass_a(
    const __bf16* __restrict__ hcat, const __bf16* __restrict__ h2oT,
    float* __restrict__ Asum) {
    const int tid = threadIdx.x;
    const int wave = tid >> 6, lane = tid & 63;
    const int wm = wave >> 1, wn = wave & 1;
    const int lg = lane >> 4, lr = lane & 15;
    const int rowbase = blockIdx.y * 64;
    bf16x8 bfr[8][2];
    load_bfrag(h2oT, blockIdx.x, wn, lg, lr, bfr);
    f32x4 acc[2][8];
    tile_gemm(hcat, rowbase, wm, lg, lr, bfr, acc);
    float rs[2][4];
#pragma unroll
    for (int m = 0; m < 2; ++m)
#pragma unroll
        for (int r = 0; r < 4; ++r) {
            float s = 0.f;
#pragma unroll
            for (int n = 0; n < 8; ++n) s += __expf(acc[m][n][r]);
            rs[m][r] = s;
        }
#pragma unroll
    for (int mask = 1; mask < 16; mask <<= 1)
#pragma unroll
        for (int m = 0; m < 2; ++m)
#pragma unroll
            for (int r = 0; r < 4; ++r)
                rs[m][r] += __shfl_xor(rs[m][r], mask, 64);
    __shared__ float tsum[2][64];
    if (lr == 0) {
#pragma unroll
        for (int m = 0; m < 2; ++m)
#pragma unroll
            for (int r = 0; r < 4; ++r)
                tsum[wn][wm * 32 + m * 16 + lg * 4 + r] = rs[m][r];
    }
    __syncthreads();
    if (tid < 64)
        Asum[blockIdx.x * M_TOT + rowbase + tid] = tsum[0][tid] + tsum[1][tid];
}

// ---------------------------------------------------------------------------
// Kernel 3: reduce partials over 125 v-tiles -> lse[row] = log(sum)
// ---------------------------------------------------------------------------
__global__ __launch_bounds__(256) void k_lse(
    const float* __restrict__ Asum, float* __restrict__ lse) {
    const int row = blockIdx.x * 256 + threadIdx.x;
    float s = 0.f;
    for (int i = 0; i < NVT; ++i) s += Asum[i * M_TOT + row];
    lse[row] = logf(s);
}

// ---------------------------------------------------------------------------
// Kernel 4 (pass B): recompute logits, store acc-lse DIRECTLY (no LDS).
// Per wave-store: 4 rows x 64B; n-inner ordering gives 512B runs per row
// that L2 write-combines into full lines.
// ---------------------------------------------------------------------------
__global__ __launch_bounds__(256) void k_pass_b(
    const __bf16* __restrict__ hcat, const __bf16* __restrict__ h2oT,
    const float* __restrict__ lse, float* __restrict__ out) {
    const int tid = threadIdx.x;
    const int wave = tid >> 6, lane = tid & 63;
    const int wm = wave >> 1, wn = wave & 1;
    const int lg = lane >> 4, lr = lane & 15;
    const int rowbase = blockIdx.y * 64;
    const int colbase = blockIdx.x * 256;
    bf16x8 bfr[8][2];
    load_bfrag(h2oT, blockIdx.x, wn, lg, lr, bfr);
    f32x4 acc[2][8];
    tile_gemm(hcat, rowbase, wm, lg, lr, bfr, acc);
    float lsev[2][4];
#pragma unroll
    for (int m = 0; m < 2; ++m)
#pragma unroll
        for (int r = 0; r < 4; ++r)
            lsev[m][r] = lse[rowbase + wm * 32 + m * 16 + lg * 4 + r];
#pragma unroll
    for (int m = 0; m < 2; ++m)
#pragma unroll
        for (int r = 0; r < 4; ++r) {
            const int row = rowbase + wm * 32 + m * 16 + lg * 4 + r;
            float* rp = out + (size_t)row * V_SZ + colbase + wn * 128 + lr;
#pragma unroll
            for (int n = 0; n < 8; ++n)
                rp[n * 16] = acc[m][n][r] - lsev[m][r];
        }
}

// ---------------------------------------------------------------------------
extern "C" void kernel_launch(void* const* d_in, const int* in_sizes, int n_in,
                              void* d_out, int out_size, void* d_ws, size_t ws_size,
                              hipStream_t stream) {
    (void)in_sizes; (void)n_in; (void)out_size; (void)ws_size;
    const int*   inp   = (const int*)d_in[0];
    const float* we    = (const float*)d_in[1];
    const float* i2h1  = (const float*)d_in[2];
    const float* i2h2  = (const float*)d_in[3];
    const float* h2o   = (const float*)d_in[4];
    const float* bias  = (const float*)d_in[5];
    const float* hinit = (const float*)d_in[6];
    float* out = (float*)d_out;
    char* ws = (char*)d_ws;
    unsigned short* hcat_u = (unsigned short*)(ws);           // 262144 B
    unsigned short* h2oT_u = (unsigned short*)(ws + 262144);  // 4096000 B
    float*          Asum   = (float*)(ws + 4358144);          // 1024000 B
    float*          lse    = (float*)(ws + 5382144);          // 8192 B

    k_prep_rnn<<<157, 256, 0, stream>>>(inp, we, i2h1, i2h2, h2o, bias, hinit,
                                        hcat_u, h2oT_u);
    k_pass_a<<<dim3(NVT, NMT), 256, 0, stream>>>(
        (const __bf16*)hcat_u, (const __bf16*)h2oT_u, Asum);
    k_lse<<<8, 256, 0, stream>>>(Asum, lse);
    k_pass_b<<<dim3(NVT, NMT), 256, 0, stream>>>(
        (const __bf16*)hcat_u, (const __bf16*)h2oT_u, lse, out);
}